// Round 1
// baseline (878.925 us; speedup 1.0000x reference)
//
#include <hip/hip_runtime.h>

#define THREADS 256

// Pass over edges: deg[col] += w   (vectorized 4 edges/thread)
__global__ void deg_kernel(const int* __restrict__ col, const float* __restrict__ w,
                           float* __restrict__ deg, int E) {
    int i4 = (blockIdx.x * blockDim.x + threadIdx.x) * 4;
    if (i4 + 3 < E) {
        int4   c  = *(const int4*)(col + i4);
        float4 wv = *(const float4*)(w + i4);
        atomicAdd(&deg[c.x], wv.x);
        atomicAdd(&deg[c.y], wv.y);
        atomicAdd(&deg[c.z], wv.z);
        atomicAdd(&deg[c.w], wv.w);
    } else {
        for (int e = i4; e < E; ++e) atomicAdd(&deg[col[e]], w[e]);
    }
}

// Per-node: dinv = rsqrt(deg + 1 /*self-loop*/); p = dinv * x  (deg overwritten in place)
__global__ void dinv_kernel(const float* __restrict__ x, float* __restrict__ deg_dinv,
                            float* __restrict__ p, int N) {
    int i = blockIdx.x * blockDim.x + threadIdx.x;
    if (i < N) {
        float d  = deg_dinv[i] + 1.0f;
        float di = d > 0.0f ? rsqrtf(d) : 0.0f;
        deg_dinv[i] = di;
        p[i] = di * x[i];
    }
}

// Generic normalized scatter pass: out[col] += src[row] * w * dinv[col]
// (src is already pre-scaled by dinv on the source side)
__global__ void agg_kernel(const int* __restrict__ row, const int* __restrict__ col,
                           const float* __restrict__ w, const float* __restrict__ src,
                           const float* __restrict__ dinv, float* __restrict__ out, int E) {
    int i4 = (blockIdx.x * blockDim.x + threadIdx.x) * 4;
    if (i4 + 3 < E) {
        int4   r  = *(const int4*)(row + i4);
        int4   c  = *(const int4*)(col + i4);
        float4 wv = *(const float4*)(w + i4);
        atomicAdd(&out[c.x], src[r.x] * wv.x * dinv[c.x]);
        atomicAdd(&out[c.y], src[r.y] * wv.y * dinv[c.y]);
        atomicAdd(&out[c.z], src[r.z] * wv.z * dinv[c.z]);
        atomicAdd(&out[c.w], src[r.w] * wv.w * dinv[c.w]);
    } else {
        for (int e = i4; e < E; ++e)
            atomicAdd(&out[col[e]], src[row[e]] * w[e] * dinv[col[e]]);
    }
}

// Per-node MLP between the two aggregations:
//   s = s1 + dinv*p (self-loop term of layer 1)
//   t = sum_k relu(s*W1[k] + b1[k]) * W2[k]
//   q = dinv * t   (pre-scale for the second aggregation)
__global__ void mlp_kernel(const float* __restrict__ s1, const float* __restrict__ dinv,
                           const float* __restrict__ p,
                           const float* __restrict__ W1, const float* __restrict__ b1,
                           const float* __restrict__ W2,
                           float* __restrict__ q, int N) {
    int i = blockIdx.x * blockDim.x + threadIdx.x;
    if (i < N) {
        float di = dinv[i];
        float s  = s1[i] + di * p[i];
        float acc = 0.0f;
#pragma unroll
        for (int k = 0; k < 16; ++k) {
            float h = fmaxf(s * W1[k] + b1[k], 0.0f);
            acc += h * W2[k];
        }
        q[i] = di * acc;
    }
}

// out[i] += dinv[i]*q[i] (layer-2 self-loop) + b2
__global__ void fin_kernel(const float* __restrict__ dinv, const float* __restrict__ q,
                           const float* __restrict__ b2, float* __restrict__ out, int N) {
    int i = blockIdx.x * blockDim.x + threadIdx.x;
    if (i < N) out[i] += dinv[i] * q[i] + b2[0];
}

extern "C" void kernel_launch(void* const* d_in, const int* in_sizes, int n_in,
                              void* d_out, int out_size, void* d_ws, size_t ws_size,
                              hipStream_t stream) {
    const float* x  = (const float*)d_in[0];
    const int*   ei = (const int*)  d_in[1];
    const float* ew = (const float*)d_in[2];
    const float* W1 = (const float*)d_in[3];
    const float* b1 = (const float*)d_in[4];
    const float* W2 = (const float*)d_in[5];
    const float* b2 = (const float*)d_in[6];

    const int N = in_sizes[0];       // x is [N,1]
    const int E = in_sizes[2];       // edge_attr is [E]
    const int* row = ei;             // edge_index[0] = source
    const int* col = ei + E;         // edge_index[1] = target

    float* f    = (float*)d_ws;
    float* dinv = f;                 // deg accumulator, then dinv (in place)
    float* p    = f + (size_t)N;     // dinv * x
    float* s1   = f + (size_t)2*N;   // layer-1 aggregated scalar
    float* q    = f + (size_t)3*N;   // dinv * t

    float* out = (float*)d_out;

    // d_ws / d_out are poisoned 0xAA before every launch — zero the accumulators.
    hipMemsetAsync(dinv, 0, (size_t)N * sizeof(float), stream);
    hipMemsetAsync(s1,   0, (size_t)N * sizeof(float), stream);
    hipMemsetAsync(out,  0, (size_t)N * sizeof(float), stream);

    const int eb = ((E + 3) / 4 + THREADS - 1) / THREADS;
    const int nb = (N + THREADS - 1) / THREADS;

    deg_kernel <<<eb, THREADS, 0, stream>>>(col, ew, dinv, E);
    dinv_kernel<<<nb, THREADS, 0, stream>>>(x, dinv, p, N);
    agg_kernel <<<eb, THREADS, 0, stream>>>(row, col, ew, p, dinv, s1, E);
    mlp_kernel <<<nb, THREADS, 0, stream>>>(s1, dinv, p, W1, b1, W2, q, N);
    agg_kernel <<<eb, THREADS, 0, stream>>>(row, col, ew, q, dinv, out, E);
    fin_kernel <<<nb, THREADS, 0, stream>>>(dinv, q, b2, out, N);
}

// Round 2
// 841.611 us; speedup vs baseline: 1.0443x; 1.0443x over previous
//
#include <hip/hip_runtime.h>

#define THREADS 256
#define NXCD 8

// Hardware XCD id (0..7 on MI355X) — measured via s_getreg(HW_REG_XCC_ID).
// All waves of a workgroup live on one CU, hence one XCD, so this is
// wave-uniform and workgroup-uniform.
__device__ __forceinline__ int xcd_id() {
    int x;
    asm volatile("s_getreg_b32 %0, hwreg(HW_REG_XCC_ID)" : "=s"(x));
    return x & (NXCD - 1);
}

// Workgroup-scope relaxed fp32 atomic: executes the RMW in the local XCD's
// L2 (no cross-XCD coherency bit). Only safe because each XCD owns its own
// partial array.
__device__ __forceinline__ void atom_add_local(float* p, float v) {
    __hip_atomic_fetch_add(p, v, __ATOMIC_RELAXED, __HIP_MEMORY_SCOPE_WORKGROUP);
}

// ---------- edge passes (XCD-local partial accumulation) ----------

// part[xcd][col] += w
__global__ void e_deg(const int* __restrict__ col, const float* __restrict__ w,
                      float* __restrict__ part, int E, int N) {
    float* mp = part + (size_t)xcd_id() * N;
    int i4 = (blockIdx.x * blockDim.x + threadIdx.x) * 4;
    if (i4 + 3 < E) {
        int4   c  = *(const int4*)(col + i4);
        float4 wv = *(const float4*)(w + i4);
        atom_add_local(&mp[c.x], wv.x);
        atom_add_local(&mp[c.y], wv.y);
        atom_add_local(&mp[c.z], wv.z);
        atom_add_local(&mp[c.w], wv.w);
    } else {
        for (int e = i4; e < E; ++e) atom_add_local(&mp[col[e]], w[e]);
    }
}

// part[xcd][col] += src[row] * w * dinv[col]   (src already pre-scaled by dinv)
__global__ void e_agg(const int* __restrict__ row, const int* __restrict__ col,
                      const float* __restrict__ w, const float* __restrict__ src,
                      const float* __restrict__ dinv, float* __restrict__ part,
                      int E, int N) {
    float* mp = part + (size_t)xcd_id() * N;
    int i4 = (blockIdx.x * blockDim.x + threadIdx.x) * 4;
    if (i4 + 3 < E) {
        int4   r  = *(const int4*)(row + i4);
        int4   c  = *(const int4*)(col + i4);
        float4 wv = *(const float4*)(w + i4);
        atom_add_local(&mp[c.x], src[r.x] * wv.x * dinv[c.x]);
        atom_add_local(&mp[c.y], src[r.y] * wv.y * dinv[c.y]);
        atom_add_local(&mp[c.z], src[r.z] * wv.z * dinv[c.z]);
        atom_add_local(&mp[c.w], src[r.w] * wv.w * dinv[c.w]);
    } else {
        for (int e = i4; e < E; ++e)
            atom_add_local(&mp[col[e]], src[row[e]] * w[e] * dinv[col[e]]);
    }
}

// ---------- node passes (reduce 8 partials + pointwise) ----------

__device__ __forceinline__ float reduce8(const float* __restrict__ part, int i, int N) {
    float s = 0.0f;
#pragma unroll
    for (int x = 0; x < NXCD; ++x) s += part[(size_t)x * N + i];
    return s;
}

// deg = sum(part) + 1 (self-loop); dinv = rsqrt(deg); p = dinv * x
__global__ void n_dinv(const float* __restrict__ part, const float* __restrict__ x,
                       float* __restrict__ dinv, float* __restrict__ p, int N) {
    int i = blockIdx.x * blockDim.x + threadIdx.x;
    if (i < N) {
        float d  = reduce8(part, i, N) + 1.0f;
        float di = d > 0.0f ? rsqrtf(d) : 0.0f;
        dinv[i] = di;
        p[i] = di * x[i];
    }
}

// s = sum(part) + dinv*p (self-loop of layer 1); 16-wide MLP; q = dinv * t
__global__ void n_mlp(const float* __restrict__ part, const float* __restrict__ dinv,
                      const float* __restrict__ p,
                      const float* __restrict__ W1, const float* __restrict__ b1,
                      const float* __restrict__ W2,
                      float* __restrict__ q, int N) {
    int i = blockIdx.x * blockDim.x + threadIdx.x;
    if (i < N) {
        float di = dinv[i];
        float s  = reduce8(part, i, N) + di * p[i];
        float acc = 0.0f;
#pragma unroll
        for (int k = 0; k < 16; ++k) {
            float h = fmaxf(s * W1[k] + b1[k], 0.0f);
            acc += h * W2[k];
        }
        q[i] = di * acc;
    }
}

// out = sum(part) + dinv*q (self-loop of layer 2) + b2
__global__ void n_out(const float* __restrict__ part, const float* __restrict__ dinv,
                      const float* __restrict__ q, const float* __restrict__ b2,
                      float* __restrict__ out, int N) {
    int i = blockIdx.x * blockDim.x + threadIdx.x;
    if (i < N) out[i] = reduce8(part, i, N) + dinv[i] * q[i] + b2[0];
}

extern "C" void kernel_launch(void* const* d_in, const int* in_sizes, int n_in,
                              void* d_out, int out_size, void* d_ws, size_t ws_size,
                              hipStream_t stream) {
    const float* x  = (const float*)d_in[0];
    const int*   ei = (const int*)  d_in[1];
    const float* ew = (const float*)d_in[2];
    const float* W1 = (const float*)d_in[3];
    const float* b1 = (const float*)d_in[4];
    const float* W2 = (const float*)d_in[5];
    const float* b2 = (const float*)d_in[6];

    const int N = in_sizes[0];       // x is [N,1]
    const int E = in_sizes[2];       // edge_attr is [E]
    const int* row = ei;             // edge_index[0] = source
    const int* col = ei + E;         // edge_index[1] = target

    float* f    = (float*)d_ws;
    float* part = f;                       // [8][N] XCD-local partials (reused 3x)
    float* dinv = f + (size_t)NXCD * N;
    float* p    = dinv + (size_t)N;        // dinv * x
    float* q    = p    + (size_t)N;        // dinv * t

    float* out = (float*)d_out;

    const size_t part_bytes = (size_t)NXCD * N * sizeof(float);
    const int eb = ((E + 3) / 4 + THREADS - 1) / THREADS;
    const int nb = (N + THREADS - 1) / THREADS;

    // Pass 1: degree
    hipMemsetAsync(part, 0, part_bytes, stream);
    e_deg <<<eb, THREADS, 0, stream>>>(col, ew, part, E, N);
    n_dinv<<<nb, THREADS, 0, stream>>>(part, x, dinv, p, N);

    // Pass 2: layer-1 aggregation + MLP
    hipMemsetAsync(part, 0, part_bytes, stream);
    e_agg <<<eb, THREADS, 0, stream>>>(row, col, ew, p, dinv, part, E, N);
    n_mlp <<<nb, THREADS, 0, stream>>>(part, dinv, p, W1, b1, W2, q, N);

    // Pass 3: layer-2 aggregation + epilogue
    hipMemsetAsync(part, 0, part_bytes, stream);
    e_agg <<<eb, THREADS, 0, stream>>>(row, col, ew, q, dinv, part, E, N);
    n_out <<<nb, THREADS, 0, stream>>>(part, dinv, q, b2, out, N);
}

// Round 3
// 286.650 us; speedup vs baseline: 3.0662x; 2.9360x over previous
//
#include <hip/hip_runtime.h>

#define THREADS 256
#define BSHIFT  12
#define BSIZE   4096            // nodes per bucket
#define MAXNB   32              // max buckets (N<=131072)
#define M       32              // accumulate slices per bucket
#define EPB     2048            // edges per count/scatter block
#define EPT     (EPB / THREADS) // 8 edges per thread

// ---------- pass 1: bucket histogram ----------
__global__ void k_count(const int* __restrict__ col, int* __restrict__ cnt,
                        int E, int nb) {
    __shared__ int hist[MAXNB];
    int t = threadIdx.x;
    if (t < nb) hist[t] = 0;
    __syncthreads();
    int base = blockIdx.x * EPB;
#pragma unroll
    for (int k = 0; k < EPT; ++k) {
        int e = base + t + k * THREADS;
        if (e < E) atomicAdd(&hist[col[e] >> BSHIFT], 1);
    }
    __syncthreads();
    if (t < nb && hist[t]) atomicAdd(&cnt[t], hist[t]);
}

// ---------- pass 2: exclusive scan (tiny) ----------
__global__ void k_scan(const int* __restrict__ cnt, int* __restrict__ starts,
                       int* __restrict__ cur, int nb) {
    if (threadIdx.x == 0) {
        int s = 0;
        for (int b = 0; b < nb; ++b) { starts[b] = s; cur[b] = s; s += cnt[b]; }
        starts[nb] = s;
    }
}

// ---------- pass 3: scatter edges into bucket order ----------
// record: packed = (col & 4095) << 17 | row   (row < 2^17), plus w
__global__ void k_scatter(const int* __restrict__ row, const int* __restrict__ col,
                          const float* __restrict__ w, int* __restrict__ cur,
                          int* __restrict__ packed, float* __restrict__ wrec,
                          int E, int nb) {
    __shared__ int hist[MAXNB];
    __shared__ int rbase[MAXNB];
    int t = threadIdx.x;
    if (t < nb) hist[t] = 0;
    __syncthreads();
    int base = blockIdx.x * EPB;
    int  b_[EPT], rk_[EPT], pk_[EPT];
    float w_[EPT];
#pragma unroll
    for (int k = 0; k < EPT; ++k) {
        int e = base + t + k * THREADS;
        if (e < E) {
            int c = col[e];
            int b = c >> BSHIFT;
            b_[k]  = b;
            rk_[k] = atomicAdd(&hist[b], 1);          // within-block rank
            pk_[k] = ((c & (BSIZE - 1)) << 17) | row[e];
            w_[k]  = w[e];
        } else b_[k] = -1;
    }
    __syncthreads();
    if (t < nb) rbase[t] = hist[t] ? atomicAdd(&cur[t], hist[t]) : 0;
    __syncthreads();
#pragma unroll
    for (int k = 0; k < EPT; ++k) {
        if (b_[k] >= 0) {
            int pos = rbase[b_[k]] + rk_[k];
            packed[pos] = pk_[k];
            wrec[pos]   = w_[k];
        }
    }
}

// ---------- accumulate: LDS scatter-add over one bucket slice ----------
// src == nullptr -> degree mode (v = w); else v = w * src[row]
__global__ void k_acc(const int* __restrict__ packed, const float* __restrict__ wrec,
                      const int* __restrict__ starts, const int* __restrict__ cnt,
                      const float* __restrict__ src, float* __restrict__ part) {
    __shared__ float acc[BSIZE];
    int b = blockIdx.x / M, m = blockIdx.x % M;
    for (int j = threadIdx.x; j < BSIZE; j += THREADS) acc[j] = 0.0f;
    __syncthreads();
    int s = starts[b], c = cnt[b];
    int chunk = (c + M - 1) / M;
    int lo = s + m * chunk;
    int hi = min(s + c, lo + chunk);
    for (int i = lo + threadIdx.x; i < hi; i += THREADS) {
        int   pk = packed[i];
        float v  = wrec[i];
        if (src) v *= src[pk & 0x1FFFF];
        atomicAdd(&acc[((unsigned)pk) >> 17], v);     // ds_add_f32, no return
    }
    __syncthreads();
    float* dst = part + (size_t)blockIdx.x * BSIZE;
    for (int j = threadIdx.x; j < BSIZE; j += THREADS) dst[j] = acc[j];
}

// ---------- reduce helpers ----------
__device__ __forceinline__ float reduceM(const float* __restrict__ part, int n) {
    int b = n >> BSHIFT, ofs = n & (BSIZE - 1);
    const float* pp = part + (size_t)b * M * BSIZE + ofs;
    float s = 0.0f;
#pragma unroll
    for (int m = 0; m < M; ++m) s += pp[(size_t)m * BSIZE];
    return s;
}

// deg = sum + 1 (self-loop); dinv = rsqrt(deg); p = dinv * x
__global__ void k_red_dinv(const float* __restrict__ part, const float* __restrict__ x,
                           float* __restrict__ dinv, float* __restrict__ p, int N) {
    int i = blockIdx.x * blockDim.x + threadIdx.x;
    if (i < N) {
        float d  = reduceM(part, i) + 1.0f;
        float di = rsqrtf(d);
        dinv[i] = di;
        p[i] = di * x[i];
    }
}

// s = dinv*(sum) + dinv*p (self-loop); 16-wide MLP; q = dinv * t
__global__ void k_red_mlp(const float* __restrict__ part, const float* __restrict__ dinv,
                          const float* __restrict__ p,
                          const float* __restrict__ W1, const float* __restrict__ b1,
                          const float* __restrict__ W2,
                          float* __restrict__ q, int N) {
    int i = blockIdx.x * blockDim.x + threadIdx.x;
    if (i < N) {
        float di = dinv[i];
        float s  = di * reduceM(part, i) + di * p[i];
        float acc = 0.0f;
#pragma unroll
        for (int k = 0; k < 16; ++k) {
            float h = fmaxf(s * W1[k] + b1[k], 0.0f);
            acc += h * W2[k];
        }
        q[i] = di * acc;
    }
}

// out = dinv*(sum) + dinv*q (self-loop) + b2
__global__ void k_red_out(const float* __restrict__ part, const float* __restrict__ dinv,
                          const float* __restrict__ q, const float* __restrict__ b2,
                          float* __restrict__ out, int N) {
    int i = blockIdx.x * blockDim.x + threadIdx.x;
    if (i < N) {
        float di = dinv[i];
        out[i] = di * reduceM(part, i) + di * q[i] + b2[0];
    }
}

extern "C" void kernel_launch(void* const* d_in, const int* in_sizes, int n_in,
                              void* d_out, int out_size, void* d_ws, size_t ws_size,
                              hipStream_t stream) {
    const float* x  = (const float*)d_in[0];
    const int*   ei = (const int*)  d_in[1];
    const float* ew = (const float*)d_in[2];
    const float* W1 = (const float*)d_in[3];
    const float* b1 = (const float*)d_in[4];
    const float* W2 = (const float*)d_in[5];
    const float* b2 = (const float*)d_in[6];

    const int N = in_sizes[0];       // x is [N,1]
    const int E = in_sizes[2];       // edge_attr is [E]
    const int* row = ei;             // edge_index[0] = source
    const int* col = ei + E;         // edge_index[1] = target
    const int nb = (N + BSIZE - 1) >> BSHIFT;   // 25 for N=100000

    // workspace layout
    char* wsp = (char*)d_ws;
    int*   packed = (int*)wsp;                         wsp += (size_t)E * 4;
    float* wrec   = (float*)wsp;                       wsp += (size_t)E * 4;
    float* part   = (float*)wsp;                       wsp += (size_t)nb * M * BSIZE * 4;
    float* dinv   = (float*)wsp;                       wsp += (size_t)N * 4;
    float* p      = (float*)wsp;                       wsp += (size_t)N * 4;
    float* q      = (float*)wsp;                       wsp += (size_t)N * 4;
    int*   cnt    = (int*)wsp;                         wsp += MAXNB * 4;
    int*   starts = (int*)wsp;                         wsp += (MAXNB + 1) * 4;
    int*   cur    = (int*)wsp;

    float* out = (float*)d_out;

    const int eb = (E + EPB - 1) / EPB;               // 2442
    const int nbk = (N + THREADS - 1) / THREADS;      // 391
    const int ab  = nb * M;                           // 800

    hipMemsetAsync(cnt, 0, MAXNB * sizeof(int), stream);

    k_count  <<<eb, THREADS, 0, stream>>>(col, cnt, E, nb);
    k_scan   <<<1, 64, 0, stream>>>(cnt, starts, cur, nb);
    k_scatter<<<eb, THREADS, 0, stream>>>(row, col, ew, cur, packed, wrec, E, nb);

    // degree
    k_acc     <<<ab, THREADS, 0, stream>>>(packed, wrec, starts, cnt, nullptr, part);
    k_red_dinv<<<nbk, THREADS, 0, stream>>>(part, x, dinv, p, N);

    // layer 1
    k_acc    <<<ab, THREADS, 0, stream>>>(packed, wrec, starts, cnt, p, part);
    k_red_mlp<<<nbk, THREADS, 0, stream>>>(part, dinv, p, W1, b1, W2, q, N);

    // layer 2
    k_acc    <<<ab, THREADS, 0, stream>>>(packed, wrec, starts, cnt, q, part);
    k_red_out<<<nbk, THREADS, 0, stream>>>(part, dinv, q, b2, out, N);
}

// Round 4
// 282.557 us; speedup vs baseline: 3.1106x; 1.0145x over previous
//
#include <hip/hip_runtime.h>

#define THREADS 256
#define BSHIFT  12
#define BSIZE   4096            // nodes per bucket
#define MAXNB   32              // max buckets (N<=131072)
#define M       32              // accumulate slices per bucket
#define EPB     2048            // edges per count/scatter block
#define EPT     (EPB / THREADS) // 8 edges per thread

// ---------- pass 1: bucket histogram ----------
__global__ void k_count(const int* __restrict__ col, int* __restrict__ cnt,
                        int E, int nb) {
    __shared__ int hist[MAXNB];
    int t = threadIdx.x;
    if (t < nb) hist[t] = 0;
    __syncthreads();
    int base = blockIdx.x * EPB;
    if (base + EPB <= E) {
#pragma unroll
        for (int k = 0; k < EPT / 4; ++k) {
            int4 c = *(const int4*)(col + base + (t + k * THREADS) * 4);
            atomicAdd(&hist[c.x >> BSHIFT], 1);
            atomicAdd(&hist[c.y >> BSHIFT], 1);
            atomicAdd(&hist[c.z >> BSHIFT], 1);
            atomicAdd(&hist[c.w >> BSHIFT], 1);
        }
    } else {
#pragma unroll
        for (int k = 0; k < EPT; ++k) {
            int e = base + t + k * THREADS;
            if (e < E) atomicAdd(&hist[col[e] >> BSHIFT], 1);
        }
    }
    __syncthreads();
    if (t < nb && hist[t]) atomicAdd(&cnt[t], hist[t]);
}

// ---------- pass 2: exclusive scan (tiny) ----------
__global__ void k_scan(const int* __restrict__ cnt, int* __restrict__ starts,
                       int* __restrict__ cur, int nb) {
    if (threadIdx.x == 0) {
        int s = 0;
        for (int b = 0; b < nb; ++b) { starts[b] = s; cur[b] = s; s += cnt[b]; }
        starts[nb] = s;
    }
}

// ---------- pass 3: scatter edges into bucket order ----------
// record.x = (col & 4095) << 17 | row  (row < 2^17),  record.y = bits(w)
// Block-local bucket sort in LDS, then coalesced 8 B stores.
__global__ void k_scatter(const int* __restrict__ row, const int* __restrict__ col,
                          const float* __restrict__ w, int* __restrict__ cur,
                          int2* __restrict__ rec, int E, int nb) {
    __shared__ int  hist[MAXNB];
    __shared__ int  lofs[MAXNB + 1];
    __shared__ int  rbase[MAXNB];
    __shared__ int2 buf[EPB];          // 16 KB
    int t = threadIdx.x;
    if (t < nb) hist[t] = 0;
    __syncthreads();
    int base = blockIdx.x * EPB;

    int  b_[EPT], rk_[EPT], pk_[EPT];
    float w_[EPT];
#pragma unroll
    for (int k = 0; k < EPT; ++k) {
        int e = base + t + k * THREADS;
        if (e < E) {
            int c = col[e];
            int b = c >> BSHIFT;
            b_[k]  = b;
            rk_[k] = atomicAdd(&hist[b], 1);          // within-block rank
            pk_[k] = ((c & (BSIZE - 1)) << 17) | row[e];
            w_[k]  = w[e];
        } else b_[k] = -1;
    }
    __syncthreads();
    if (t == 0) {                                      // 25-entry serial scan
        int s = 0;
        for (int b = 0; b < nb; ++b) { lofs[b] = s; s += hist[b]; }
        lofs[nb] = s;
    }
    if (t < nb) rbase[t] = hist[t] ? atomicAdd(&cur[t], hist[t]) : 0;
    __syncthreads();
    // write records into LDS in bucket-sorted order
#pragma unroll
    for (int k = 0; k < EPT; ++k) {
        if (b_[k] >= 0)
            buf[lofs[b_[k]] + rk_[k]] = make_int2(pk_[k], __float_as_int(w_[k]));
    }
    __syncthreads();
    // coalesced copy-out: consecutive threads -> consecutive global addresses
    int total = lofs[nb];
    for (int j = t; j < total; j += THREADS) {
        // binary search: bucket b with lofs[b] <= j < lofs[b+1]
        int lo = 0, hi = nb;
        while (hi - lo > 1) { int mid = (lo + hi) >> 1; if (lofs[mid] <= j) lo = mid; else hi = mid; }
        rec[rbase[lo] + (j - lofs[lo])] = buf[j];
    }
}

// ---------- accumulate: LDS scatter-add over one bucket slice ----------
template <bool HAS_SRC>
__global__ void k_acc(const int2* __restrict__ rec,
                      const int* __restrict__ starts, const int* __restrict__ cnt,
                      const float* __restrict__ src, float* __restrict__ part) {
    __shared__ float acc[BSIZE];
    int b = blockIdx.x / M, m = blockIdx.x % M;
    for (int j = threadIdx.x; j < BSIZE; j += THREADS) acc[j] = 0.0f;
    __syncthreads();
    int s = starts[b], c = cnt[b];
    int chunk = (c + M - 1) / M;
    int lo = s + m * chunk;
    int hi = min(s + c, lo + chunk);
    for (int i = lo + threadIdx.x; i < hi; i += THREADS) {
        int2  r = rec[i];
        float v = __int_as_float(r.y);
        if (HAS_SRC) v *= src[r.x & 0x1FFFF];
        atomicAdd(&acc[((unsigned)r.x) >> 17], v);    // ds_add_f32, no return
    }
    __syncthreads();
    float* dst = part + (size_t)blockIdx.x * BSIZE;
    for (int j = threadIdx.x; j < BSIZE; j += THREADS) dst[j] = acc[j];
}

// ---------- reduce helpers ----------
__device__ __forceinline__ float reduceM(const float* __restrict__ part, int n) {
    int b = n >> BSHIFT, ofs = n & (BSIZE - 1);
    const float* pp = part + (size_t)b * M * BSIZE + ofs;
    float s = 0.0f;
#pragma unroll
    for (int m = 0; m < M; ++m) s += pp[(size_t)m * BSIZE];
    return s;
}

// deg = sum + 1 (self-loop); dinv = rsqrt(deg); p = dinv * x
__global__ void k_red_dinv(const float* __restrict__ part, const float* __restrict__ x,
                           float* __restrict__ dinv, float* __restrict__ p, int N) {
    int i = blockIdx.x * blockDim.x + threadIdx.x;
    if (i < N) {
        float d  = reduceM(part, i) + 1.0f;
        float di = rsqrtf(d);
        dinv[i] = di;
        p[i] = di * x[i];
    }
}

// s = dinv*(sum) + dinv*p (self-loop); 16-wide MLP; q = dinv * t
__global__ void k_red_mlp(const float* __restrict__ part, const float* __restrict__ dinv,
                          const float* __restrict__ p,
                          const float* __restrict__ W1, const float* __restrict__ b1,
                          const float* __restrict__ W2,
                          float* __restrict__ q, int N) {
    int i = blockIdx.x * blockDim.x + threadIdx.x;
    if (i < N) {
        float di = dinv[i];
        float s  = di * reduceM(part, i) + di * p[i];
        float acc = 0.0f;
#pragma unroll
        for (int k = 0; k < 16; ++k) {
            float h = fmaxf(s * W1[k] + b1[k], 0.0f);
            acc += h * W2[k];
        }
        q[i] = di * acc;
    }
}

// out = dinv*(sum) + dinv*q (self-loop) + b2
__global__ void k_red_out(const float* __restrict__ part, const float* __restrict__ dinv,
                          const float* __restrict__ q, const float* __restrict__ b2,
                          float* __restrict__ out, int N) {
    int i = blockIdx.x * blockDim.x + threadIdx.x;
    if (i < N) {
        float di = dinv[i];
        out[i] = di * reduceM(part, i) + di * q[i] + b2[0];
    }
}

extern "C" void kernel_launch(void* const* d_in, const int* in_sizes, int n_in,
                              void* d_out, int out_size, void* d_ws, size_t ws_size,
                              hipStream_t stream) {
    const float* x  = (const float*)d_in[0];
    const int*   ei = (const int*)  d_in[1];
    const float* ew = (const float*)d_in[2];
    const float* W1 = (const float*)d_in[3];
    const float* b1 = (const float*)d_in[4];
    const float* W2 = (const float*)d_in[5];
    const float* b2 = (const float*)d_in[6];

    const int N = in_sizes[0];       // x is [N,1]
    const int E = in_sizes[2];       // edge_attr is [E]
    const int* row = ei;             // edge_index[0] = source
    const int* col = ei + E;         // edge_index[1] = target
    const int nb = (N + BSIZE - 1) >> BSHIFT;   // 25 for N=100000

    // workspace layout
    char* wsp = (char*)d_ws;
    int2*  rec    = (int2*)wsp;                        wsp += (size_t)E * 8;
    float* part   = (float*)wsp;                       wsp += (size_t)nb * M * BSIZE * 4;
    float* dinv   = (float*)wsp;                       wsp += (size_t)N * 4;
    float* p      = (float*)wsp;                       wsp += (size_t)N * 4;
    float* q      = (float*)wsp;                       wsp += (size_t)N * 4;
    int*   cnt    = (int*)wsp;                         wsp += MAXNB * 4;
    int*   starts = (int*)wsp;                         wsp += (MAXNB + 1) * 4;
    int*   cur    = (int*)wsp;

    float* out = (float*)d_out;

    const int eb  = (E + EPB - 1) / EPB;              // 2442
    const int nbk = (N + THREADS - 1) / THREADS;      // 391
    const int ab  = nb * M;                           // 800

    hipMemsetAsync(cnt, 0, MAXNB * sizeof(int), stream);

    k_count  <<<eb, THREADS, 0, stream>>>(col, cnt, E, nb);
    k_scan   <<<1, 64, 0, stream>>>(cnt, starts, cur, nb);
    k_scatter<<<eb, THREADS, 0, stream>>>(row, col, ew, cur, rec, E, nb);

    // degree
    k_acc<false><<<ab, THREADS, 0, stream>>>(rec, starts, cnt, nullptr, part);
    k_red_dinv  <<<nbk, THREADS, 0, stream>>>(part, x, dinv, p, N);

    // layer 1
    k_acc<true><<<ab, THREADS, 0, stream>>>(rec, starts, cnt, p, part);
    k_red_mlp  <<<nbk, THREADS, 0, stream>>>(part, dinv, p, W1, b1, W2, q, N);

    // layer 2
    k_acc<true><<<ab, THREADS, 0, stream>>>(rec, starts, cnt, q, part);
    k_red_out  <<<nbk, THREADS, 0, stream>>>(part, dinv, q, b2, out, N);
}

// Round 5
// 247.894 us; speedup vs baseline: 3.5456x; 1.1398x over previous
//
#include <hip/hip_runtime.h>

#define THREADS 256
#define BSHIFT  12
#define BSIZE   4096            // nodes per bucket
#define MAXNB   32              // max buckets (N<=131072)
#define M       32              // accumulate slices per bucket
#define CAP     208896          // per-bucket record capacity: mean 204800 + 9.2 sigma
#define EPB     2048            // edges per scatter block
#define EPT     (EPB / THREADS) // 8 edges per thread

// ---------- init bucket cursors to fixed bases ----------
__global__ void k_init(int* __restrict__ cur, int nb) {
    int t = threadIdx.x;
    if (t < nb) cur[t] = t * CAP;
}

// ---------- scatter edges into fixed-capacity bucket regions ----------
// record.x = (col & 4095) << 17 | row  (row < 2^17), record.y = bits(w)
// Two-phase (histogram, then re-read+rank) to avoid per-thread array spills.
__global__ void k_scatter(const int* __restrict__ row, const int* __restrict__ col,
                          const float* __restrict__ w, int* __restrict__ cur,
                          int2* __restrict__ rec, int E, int nb) {
    __shared__ int  hist[MAXNB];
    __shared__ int  lofs[MAXNB + 1];
    __shared__ int  rbase[MAXNB];
    __shared__ int2 buf[EPB];          // 16 KB
    int t = threadIdx.x;
    if (t < MAXNB) hist[t] = 0;
    __syncthreads();
    int base = blockIdx.x * EPB;
    bool full = (base + EPB <= E);

    // phase A: block-local bucket histogram (col only, vectorized)
    if (full) {
#pragma unroll
        for (int k = 0; k < EPT / 4; ++k) {
            int4 c = *(const int4*)(col + base + (t + k * THREADS) * 4);
            atomicAdd(&hist[c.x >> BSHIFT], 1);
            atomicAdd(&hist[c.y >> BSHIFT], 1);
            atomicAdd(&hist[c.z >> BSHIFT], 1);
            atomicAdd(&hist[c.w >> BSHIFT], 1);
        }
    } else {
        for (int k = 0; k < EPT; ++k) {
            int e = base + t + k * THREADS;
            if (e < E) atomicAdd(&hist[col[e] >> BSHIFT], 1);
        }
    }
    __syncthreads();
    if (t == 0) {                      // 25-entry serial scan
        int s = 0;
        for (int b = 0; b < nb; ++b) { lofs[b] = s; s += hist[b]; }
        lofs[nb] = s;
    }
    if (t < nb) rbase[t] = hist[t] ? atomicAdd(&cur[t], hist[t]) : 0;
    __syncthreads();
    if (t < MAXNB) hist[t] = 0;        // reuse as phase-B rank counters
    __syncthreads();

    // phase B: re-read (L1-hot), rank, write bucket-sorted into LDS
    if (full) {
#pragma unroll
        for (int k = 0; k < EPT / 4; ++k) {
            int idx = base + (t + k * THREADS) * 4;
            int4   c  = *(const int4*)(col + idx);
            int4   r  = *(const int4*)(row + idx);
            float4 wv = *(const float4*)(w + idx);
            int b, rk;
            b = c.x >> BSHIFT; rk = atomicAdd(&hist[b], 1);
            buf[lofs[b] + rk] = make_int2(((c.x & (BSIZE-1)) << 17) | r.x, __float_as_int(wv.x));
            b = c.y >> BSHIFT; rk = atomicAdd(&hist[b], 1);
            buf[lofs[b] + rk] = make_int2(((c.y & (BSIZE-1)) << 17) | r.y, __float_as_int(wv.y));
            b = c.z >> BSHIFT; rk = atomicAdd(&hist[b], 1);
            buf[lofs[b] + rk] = make_int2(((c.z & (BSIZE-1)) << 17) | r.z, __float_as_int(wv.z));
            b = c.w >> BSHIFT; rk = atomicAdd(&hist[b], 1);
            buf[lofs[b] + rk] = make_int2(((c.w & (BSIZE-1)) << 17) | r.w, __float_as_int(wv.w));
        }
    } else {
        for (int k = 0; k < EPT; ++k) {
            int e = base + t + k * THREADS;
            if (e < E) {
                int c = col[e];
                int b = c >> BSHIFT;
                int rk = atomicAdd(&hist[b], 1);
                buf[lofs[b] + rk] = make_int2(((c & (BSIZE-1)) << 17) | row[e],
                                              __float_as_int(w[e]));
            }
        }
    }
    __syncthreads();

    // coalesced copy-out: consecutive threads -> consecutive global addresses
    int total = lofs[nb];
    for (int j = t; j < total; j += THREADS) {
        int lo = 0, hi = nb;
        while (hi - lo > 1) { int mid = (lo + hi) >> 1; if (lofs[mid] <= j) lo = mid; else hi = mid; }
        rec[rbase[lo] + (j - lofs[lo])] = buf[j];
    }
}

// ---------- accumulate: LDS scatter-add over one bucket slice ----------
// 4 records per thread per iteration -> 4 outstanding gathers (ILP).
template <bool HAS_SRC>
__global__ void k_acc(const int2* __restrict__ rec, const int* __restrict__ cur,
                      const float* __restrict__ src, float* __restrict__ part) {
    __shared__ float acc[BSIZE];
    int b = blockIdx.x / M, m = blockIdx.x % M;
    for (int j = threadIdx.x; j < BSIZE; j += THREADS) acc[j] = 0.0f;
    __syncthreads();
    int s = b * CAP;
    int c = cur[b] - s;
    int chunk = (((c + M - 1) / M) + 3) & ~3;      // multiple of 4
    int lo = s + m * chunk;
    int hi = min(s + c, lo + chunk);
    const int4* rec4 = (const int4*)rec;           // 2 records per int4
    int i = lo + threadIdx.x * 4;
    for (; i + 3 < hi; i += THREADS * 4) {
        int4 a = rec4[i >> 1];
        int4 d = rec4[(i >> 1) + 1];
        float v0 = __int_as_float(a.y), v1 = __int_as_float(a.w);
        float v2 = __int_as_float(d.y), v3 = __int_as_float(d.w);
        if (HAS_SRC) {
            v0 *= src[a.x & 0x1FFFF];
            v1 *= src[a.z & 0x1FFFF];
            v2 *= src[d.x & 0x1FFFF];
            v3 *= src[d.z & 0x1FFFF];
        }
        atomicAdd(&acc[((unsigned)a.x) >> 17], v0);
        atomicAdd(&acc[((unsigned)a.z) >> 17], v1);
        atomicAdd(&acc[((unsigned)d.x) >> 17], v2);
        atomicAdd(&acc[((unsigned)d.z) >> 17], v3);
    }
    for (; i < hi; ++i) {                          // <=3 leftover records
        int2 r = rec[i];
        float v = __int_as_float(r.y);
        if (HAS_SRC) v *= src[r.x & 0x1FFFF];
        atomicAdd(&acc[((unsigned)r.x) >> 17], v);
    }
    __syncthreads();
    float* dst = part + (size_t)blockIdx.x * BSIZE;
    for (int j = threadIdx.x; j < BSIZE; j += THREADS) dst[j] = acc[j];
}

// ---------- reduce helpers ----------
__device__ __forceinline__ float reduceM(const float* __restrict__ part, int n) {
    int b = n >> BSHIFT, ofs = n & (BSIZE - 1);
    const float* pp = part + (size_t)b * M * BSIZE + ofs;
    float s = 0.0f;
#pragma unroll
    for (int m = 0; m < M; ++m) s += pp[(size_t)m * BSIZE];
    return s;
}

// deg = sum + 1 (self-loop); dinv = rsqrt(deg); p = dinv * x
__global__ void k_red_dinv(const float* __restrict__ part, const float* __restrict__ x,
                           float* __restrict__ dinv, float* __restrict__ p, int N) {
    int i = blockIdx.x * blockDim.x + threadIdx.x;
    if (i < N) {
        float d  = reduceM(part, i) + 1.0f;
        float di = rsqrtf(d);
        dinv[i] = di;
        p[i] = di * x[i];
    }
}

// s = dinv*(sum) + dinv*p (self-loop); 16-wide MLP; q = dinv * t
__global__ void k_red_mlp(const float* __restrict__ part, const float* __restrict__ dinv,
                          const float* __restrict__ p,
                          const float* __restrict__ W1, const float* __restrict__ b1,
                          const float* __restrict__ W2,
                          float* __restrict__ q, int N) {
    int i = blockIdx.x * blockDim.x + threadIdx.x;
    if (i < N) {
        float di = dinv[i];
        float s  = di * reduceM(part, i) + di * p[i];
        float acc = 0.0f;
#pragma unroll
        for (int k = 0; k < 16; ++k) {
            float h = fmaxf(s * W1[k] + b1[k], 0.0f);
            acc += h * W2[k];
        }
        q[i] = di * acc;
    }
}

// out = dinv*(sum) + dinv*q (self-loop) + b2
__global__ void k_red_out(const float* __restrict__ part, const float* __restrict__ dinv,
                          const float* __restrict__ q, const float* __restrict__ b2,
                          float* __restrict__ out, int N) {
    int i = blockIdx.x * blockDim.x + threadIdx.x;
    if (i < N) {
        float di = dinv[i];
        out[i] = di * reduceM(part, i) + di * q[i] + b2[0];
    }
}

extern "C" void kernel_launch(void* const* d_in, const int* in_sizes, int n_in,
                              void* d_out, int out_size, void* d_ws, size_t ws_size,
                              hipStream_t stream) {
    const float* x  = (const float*)d_in[0];
    const int*   ei = (const int*)  d_in[1];
    const float* ew = (const float*)d_in[2];
    const float* W1 = (const float*)d_in[3];
    const float* b1 = (const float*)d_in[4];
    const float* W2 = (const float*)d_in[5];
    const float* b2 = (const float*)d_in[6];

    const int N = in_sizes[0];       // x is [N,1]
    const int E = in_sizes[2];       // edge_attr is [E]
    const int* row = ei;             // edge_index[0] = source
    const int* col = ei + E;         // edge_index[1] = target
    const int nb = (N + BSIZE - 1) >> BSHIFT;   // 25 for N=100000

    // workspace layout
    char* wsp = (char*)d_ws;
    int2*  rec  = (int2*)wsp;                          wsp += (size_t)nb * CAP * 8;
    float* part = (float*)wsp;                         wsp += (size_t)nb * M * BSIZE * 4;
    float* dinv = (float*)wsp;                         wsp += (size_t)N * 4;
    float* p    = (float*)wsp;                         wsp += (size_t)N * 4;
    float* q    = (float*)wsp;                         wsp += (size_t)N * 4;
    int*   cur  = (int*)wsp;

    float* out = (float*)d_out;

    const int eb  = (E + EPB - 1) / EPB;              // 2442
    const int nbk = (N + THREADS - 1) / THREADS;      // 391
    const int ab  = nb * M;                           // 800

    k_init   <<<1, 64, 0, stream>>>(cur, nb);
    k_scatter<<<eb, THREADS, 0, stream>>>(row, col, ew, cur, rec, E, nb);

    // degree
    k_acc<false><<<ab, THREADS, 0, stream>>>(rec, cur, nullptr, part);
    k_red_dinv  <<<nbk, THREADS, 0, stream>>>(part, x, dinv, p, N);

    // layer 1
    k_acc<true><<<ab, THREADS, 0, stream>>>(rec, cur, p, part);
    k_red_mlp  <<<nbk, THREADS, 0, stream>>>(part, dinv, p, W1, b1, W2, q, N);

    // layer 2
    k_acc<true><<<ab, THREADS, 0, stream>>>(rec, cur, q, part);
    k_red_out  <<<nbk, THREADS, 0, stream>>>(part, dinv, q, b2, out, N);
}

// Round 6
// 241.643 us; speedup vs baseline: 3.6373x; 1.0259x over previous
//
#include <hip/hip_runtime.h>

#define THREADS 256
#define BSHIFT  12
#define BSIZE   4096            // nodes per bucket
#define MAXNB   32              // max buckets (N<=131072)
#define M       32              // accumulate slices per bucket
#define NREP    64              // ticket replicas per bucket (kills same-address atomic chain)
#define EPB     2048            // edges per count/scatter block
#define EPT     (EPB / THREADS) // 8 edges per thread

// ---------- count: per-block bucket histogram + replica-spread ticketing ----------
// hr[block][bucket] = (hist, relative offset within (bucket, replica) cell)
__global__ void k_count(const int* __restrict__ col, int* __restrict__ cur,
                        int2* __restrict__ hr, int E, int nb) {
    __shared__ int hist[MAXNB];
    int t = threadIdx.x;
    if (t < MAXNB) hist[t] = 0;
    __syncthreads();
    int base = blockIdx.x * EPB;
    bool full = (base + EPB <= E);
    if (full) {
#pragma unroll
        for (int k = 0; k < EPT / 4; ++k) {
            int4 c = *(const int4*)(col + base + (t + k * THREADS) * 4);
            atomicAdd(&hist[c.x >> BSHIFT], 1);
            atomicAdd(&hist[c.y >> BSHIFT], 1);
            atomicAdd(&hist[c.z >> BSHIFT], 1);
            atomicAdd(&hist[c.w >> BSHIFT], 1);
        }
    } else {
        for (int k = 0; k < EPT; ++k) {
            int e = base + t + k * THREADS;
            if (e < E) atomicAdd(&hist[col[e] >> BSHIFT], 1);
        }
    }
    __syncthreads();
    int rep = blockIdx.x & (NREP - 1);
    if (t < nb) {
        int rel = atomicAdd(&cur[t * NREP + rep], hist[t]);   // ~39-long chain per address
        hr[blockIdx.x * MAXNB + t] = make_int2(hist[t], rel);
    }
}

// ---------- scan: exclusive prefix over nb*NREP cells, counts padded to x4 ----------
// (padding keeps every cell start a multiple of 4 records = 32 B aligned)
__global__ void k_scan(const int* __restrict__ cnt, int* __restrict__ starts, int n) {
    __shared__ int tsum[THREADS];
    int t = threadIdx.x;
    int per = (n + THREADS - 1) / THREADS;
    int lo = t * per, hi = min(n, lo + per);
    int s = 0;
    for (int i = lo; i < hi; ++i) s += (cnt[i] + 3) & ~3;
    tsum[t] = s;
    __syncthreads();
    for (int d = 1; d < THREADS; d <<= 1) {
        int v = (t >= d) ? tsum[t - d] : 0;
        __syncthreads();
        tsum[t] += v;
        __syncthreads();
    }
    int base = (t > 0) ? tsum[t - 1] : 0;
    for (int i = lo; i < hi; ++i) { starts[i] = base; base += (cnt[i] + 3) & ~3; }
}

// ---------- scatter: LDS bucket-sort, coalesced copy-out, NO global atomics ----------
// record.x = (col & 4095) << 17 | row  (row < 2^17), record.y = bits(w)
__global__ void k_scatter(const int* __restrict__ row, const int* __restrict__ col,
                          const float* __restrict__ w,
                          const int2* __restrict__ hr, const int* __restrict__ starts,
                          int2* __restrict__ rec, int E, int nb) {
    __shared__ int  lofs[MAXNB + 1];
    __shared__ int  rank[MAXNB];
    __shared__ int  rbase[MAXNB];
    __shared__ int2 buf[EPB];          // 16 KB
    __shared__ unsigned char bkt[EPB]; // 2 KB
    int t = threadIdx.x;
    if (t < MAXNB) rank[t] = 0;
    int rep = blockIdx.x & (NREP - 1);
    // wave 0: load (hist, rel), wave-scan hist -> lofs, compute global bases
    if (t < 64) {
        int h = 0, rel = 0;
        if (t < nb) {
            int2 v = hr[blockIdx.x * MAXNB + t];
            h = v.x; rel = v.y;
        }
        int inc = h;
#pragma unroll
        for (int d = 1; d < 32; d <<= 1) {
            int o = __shfl_up(inc, d, 64);
            if (t >= d) inc += o;
        }
        if (t == 0) lofs[0] = 0;
        if (t < nb) {
            lofs[t + 1] = inc;
            rbase[t] = starts[t * NREP + rep] + rel;
        }
    }
    __syncthreads();

    int base = blockIdx.x * EPB;
    bool full = (base + EPB <= E);
    if (full) {
#pragma unroll
        for (int k = 0; k < EPT / 4; ++k) {
            int idx = base + (t + k * THREADS) * 4;
            int4   c  = *(const int4*)(col + idx);
            int4   r  = *(const int4*)(row + idx);
            float4 wv = *(const float4*)(w + idx);
            int b, rk, pos;
            b = c.x >> BSHIFT; rk = atomicAdd(&rank[b], 1); pos = lofs[b] + rk;
            buf[pos] = make_int2(((c.x & (BSIZE-1)) << 17) | r.x, __float_as_int(wv.x));
            bkt[pos] = (unsigned char)b;
            b = c.y >> BSHIFT; rk = atomicAdd(&rank[b], 1); pos = lofs[b] + rk;
            buf[pos] = make_int2(((c.y & (BSIZE-1)) << 17) | r.y, __float_as_int(wv.y));
            bkt[pos] = (unsigned char)b;
            b = c.z >> BSHIFT; rk = atomicAdd(&rank[b], 1); pos = lofs[b] + rk;
            buf[pos] = make_int2(((c.z & (BSIZE-1)) << 17) | r.z, __float_as_int(wv.z));
            bkt[pos] = (unsigned char)b;
            b = c.w >> BSHIFT; rk = atomicAdd(&rank[b], 1); pos = lofs[b] + rk;
            buf[pos] = make_int2(((c.w & (BSIZE-1)) << 17) | r.w, __float_as_int(wv.w));
            bkt[pos] = (unsigned char)b;
        }
    } else {
        for (int k = 0; k < EPT; ++k) {
            int e = base + t + k * THREADS;
            if (e < E) {
                int c = col[e];
                int b = c >> BSHIFT;
                int rk = atomicAdd(&rank[b], 1);
                int pos = lofs[b] + rk;
                buf[pos] = make_int2(((c & (BSIZE-1)) << 17) | row[e], __float_as_int(w[e]));
                bkt[pos] = (unsigned char)b;
            }
        }
    }
    __syncthreads();

    int total = lofs[nb];
    for (int j = t; j < total; j += THREADS) {
        int b = bkt[j];
        rec[rbase[b] + (j - lofs[b])] = buf[j];
    }
}

// ---------- accumulate: LDS scatter-add, 8 records/thread/iter for gather ILP ----------
template <bool HAS_SRC>
__global__ void k_acc(const int2* __restrict__ rec, const int* __restrict__ cnt,
                      const int* __restrict__ starts, const float* __restrict__ src,
                      float* __restrict__ part) {
    __shared__ float acc[BSIZE];
    int b = blockIdx.x / M, m = blockIdx.x % M;
    for (int j = threadIdx.x; j < BSIZE; j += THREADS) acc[j] = 0.0f;
    __syncthreads();
    const int4* rec4 = (const int4*)rec;
#pragma unroll
    for (int rr = 0; rr < NREP / M; ++rr) {
        int cell = b * NREP + m * (NREP / M) + rr;
        int lo = starts[cell];              // multiple of 4 records (32 B aligned)
        int hi = lo + cnt[cell];
        int i = lo + threadIdx.x * 8;
        for (; i + 7 < hi; i += THREADS * 8) {
            int4 q0 = rec4[(i >> 1) + 0];
            int4 q1 = rec4[(i >> 1) + 1];
            int4 q2 = rec4[(i >> 1) + 2];
            int4 q3 = rec4[(i >> 1) + 3];
            float v0 = __int_as_float(q0.y), v1 = __int_as_float(q0.w);
            float v2 = __int_as_float(q1.y), v3 = __int_as_float(q1.w);
            float v4 = __int_as_float(q2.y), v5 = __int_as_float(q2.w);
            float v6 = __int_as_float(q3.y), v7 = __int_as_float(q3.w);
            if (HAS_SRC) {
                v0 *= src[q0.x & 0x1FFFF]; v1 *= src[q0.z & 0x1FFFF];
                v2 *= src[q1.x & 0x1FFFF]; v3 *= src[q1.z & 0x1FFFF];
                v4 *= src[q2.x & 0x1FFFF]; v5 *= src[q2.z & 0x1FFFF];
                v6 *= src[q3.x & 0x1FFFF]; v7 *= src[q3.z & 0x1FFFF];
            }
            atomicAdd(&acc[((unsigned)q0.x) >> 17], v0);
            atomicAdd(&acc[((unsigned)q0.z) >> 17], v1);
            atomicAdd(&acc[((unsigned)q1.x) >> 17], v2);
            atomicAdd(&acc[((unsigned)q1.z) >> 17], v3);
            atomicAdd(&acc[((unsigned)q2.x) >> 17], v4);
            atomicAdd(&acc[((unsigned)q2.z) >> 17], v5);
            atomicAdd(&acc[((unsigned)q3.x) >> 17], v6);
            atomicAdd(&acc[((unsigned)q3.z) >> 17], v7);
        }
        for (; i < hi; ++i) {              // <=7 leftover for the boundary-owning thread
            int2 r = rec[i];
            float v = __int_as_float(r.y);
            if (HAS_SRC) v *= src[r.x & 0x1FFFF];
            atomicAdd(&acc[((unsigned)r.x) >> 17], v);
        }
    }
    __syncthreads();
    float* dst = part + (size_t)blockIdx.x * BSIZE;
    for (int j = threadIdx.x; j < BSIZE; j += THREADS) dst[j] = acc[j];
}

// ---------- reduce helpers ----------
__device__ __forceinline__ float reduceM(const float* __restrict__ part, int n) {
    int b = n >> BSHIFT, ofs = n & (BSIZE - 1);
    const float* pp = part + (size_t)b * M * BSIZE + ofs;
    float s = 0.0f;
#pragma unroll
    for (int m = 0; m < M; ++m) s += pp[(size_t)m * BSIZE];
    return s;
}

// deg = sum + 1 (self-loop); dinv = rsqrt(deg); p = dinv * x
__global__ void k_red_dinv(const float* __restrict__ part, const float* __restrict__ x,
                           float* __restrict__ dinv, float* __restrict__ p, int N) {
    int i = blockIdx.x * blockDim.x + threadIdx.x;
    if (i < N) {
        float d  = reduceM(part, i) + 1.0f;
        float di = rsqrtf(d);
        dinv[i] = di;
        p[i] = di * x[i];
    }
}

// s = dinv*(sum) + dinv*p (self-loop); 16-wide MLP; q = dinv * t
__global__ void k_red_mlp(const float* __restrict__ part, const float* __restrict__ dinv,
                          const float* __restrict__ p,
                          const float* __restrict__ W1, const float* __restrict__ b1,
                          const float* __restrict__ W2,
                          float* __restrict__ q, int N) {
    int i = blockIdx.x * blockDim.x + threadIdx.x;
    if (i < N) {
        float di = dinv[i];
        float s  = di * reduceM(part, i) + di * p[i];
        float acc = 0.0f;
#pragma unroll
        for (int k = 0; k < 16; ++k) {
            float h = fmaxf(s * W1[k] + b1[k], 0.0f);
            acc += h * W2[k];
        }
        q[i] = di * acc;
    }
}

// out = dinv*(sum) + dinv*q (self-loop) + b2
__global__ void k_red_out(const float* __restrict__ part, const float* __restrict__ dinv,
                          const float* __restrict__ q, const float* __restrict__ b2,
                          float* __restrict__ out, int N) {
    int i = blockIdx.x * blockDim.x + threadIdx.x;
    if (i < N) {
        float di = dinv[i];
        out[i] = di * reduceM(part, i) + di * q[i] + b2[0];
    }
}

extern "C" void kernel_launch(void* const* d_in, const int* in_sizes, int n_in,
                              void* d_out, int out_size, void* d_ws, size_t ws_size,
                              hipStream_t stream) {
    const float* x  = (const float*)d_in[0];
    const int*   ei = (const int*)  d_in[1];
    const float* ew = (const float*)d_in[2];
    const float* W1 = (const float*)d_in[3];
    const float* b1 = (const float*)d_in[4];
    const float* W2 = (const float*)d_in[5];
    const float* b2 = (const float*)d_in[6];

    const int N = in_sizes[0];       // x is [N,1]
    const int E = in_sizes[2];       // edge_attr is [E]
    const int* row = ei;             // edge_index[0] = source
    const int* col = ei + E;         // edge_index[1] = target
    const int nb = (N + BSIZE - 1) >> BSHIFT;   // 25 for N=100000
    const int eb = (E + EPB - 1) / EPB;         // 2442

    // workspace layout (~55.0 MB)
    char* wsp = (char*)d_ws;
    int2*  rec    = (int2*)wsp;   wsp += (size_t)E * 8 + 65536;        // + x4-pad slack
    float* part   = (float*)wsp;  wsp += (size_t)nb * M * BSIZE * 4;
    float* dinv   = (float*)wsp;  wsp += (size_t)N * 4;
    float* p      = (float*)wsp;  wsp += (size_t)N * 4;
    float* q      = (float*)wsp;  wsp += (size_t)N * 4;
    int2*  hr     = (int2*)wsp;   wsp += (size_t)eb * MAXNB * 8;
    int*   cur    = (int*)wsp;    wsp += (size_t)nb * NREP * 4;
    int*   starts = (int*)wsp;

    float* out = (float*)d_out;

    const int nbk = (N + THREADS - 1) / THREADS;
    const int ab  = nb * M;                     // 800

    hipMemsetAsync(cur, 0, (size_t)nb * NREP * sizeof(int), stream);

    k_count  <<<eb, THREADS, 0, stream>>>(col, cur, hr, E, nb);
    k_scan   <<<1, THREADS, 0, stream>>>(cur, starts, nb * NREP);
    k_scatter<<<eb, THREADS, 0, stream>>>(row, col, ew, hr, starts, rec, E, nb);

    // degree
    k_acc<false><<<ab, THREADS, 0, stream>>>(rec, cur, starts, nullptr, part);
    k_red_dinv  <<<nbk, THREADS, 0, stream>>>(part, x, dinv, p, N);

    // layer 1
    k_acc<true><<<ab, THREADS, 0, stream>>>(rec, cur, starts, p, part);
    k_red_mlp  <<<nbk, THREADS, 0, stream>>>(part, dinv, p, W1, b1, W2, q, N);

    // layer 2
    k_acc<true><<<ab, THREADS, 0, stream>>>(rec, cur, starts, q, part);
    k_red_out  <<<nbk, THREADS, 0, stream>>>(part, dinv, q, b2, out, N);
}

// Round 9
// 240.157 us; speedup vs baseline: 3.6598x; 1.0062x over previous
//
#include <hip/hip_runtime.h>

#define T       256
#define BSHIFT  12
#define BSIZE   4096            // nodes per bucket
#define MAXNB   32              // max buckets (N<=131072)
#define M       32              // accumulate slices per bucket
#define EPB     2048            // edges per count/scatter block
#define EPT     (EPB / T)       // 8 edges per thread

// ---------- count: per-block bucket histogram -> plain-store matrix ----------
// cntT[b * ebp + g] = #edges of block g in bucket b   (transposed for scan)
__global__ void k_count(const int* __restrict__ col, int* __restrict__ cntT,
                        int E, int nb, int ebp) {
    __shared__ int hist[MAXNB];
    int t = threadIdx.x, g = blockIdx.x;
    if (t < MAXNB) hist[t] = 0;
    __syncthreads();
    int base = g * EPB;
    bool full = (base + EPB <= E);
    if (full) {
#pragma unroll
        for (int k = 0; k < EPT / 4; ++k) {
            int4 c = *(const int4*)(col + base + (t + k * T) * 4);
            atomicAdd(&hist[c.x >> BSHIFT], 1);
            atomicAdd(&hist[c.y >> BSHIFT], 1);
            atomicAdd(&hist[c.z >> BSHIFT], 1);
            atomicAdd(&hist[c.w >> BSHIFT], 1);
        }
    } else {
        for (int k = 0; k < EPT; ++k) {
            int e = base + t + k * T;
            if (e < E) atomicAdd(&hist[col[e] >> BSHIFT], 1);
        }
    }
    __syncthreads();
    if (t < nb) cntT[t * ebp + g] = hist[t];
}

// ---------- scan: one block per bucket, exclusive scan over eb blocks ----------
__global__ void k_scan(const int* __restrict__ cntT, int* __restrict__ ofsT,
                       int* __restrict__ tot, int eb, int ebp) {
    __shared__ int tsum[T];
    __shared__ int carry;
    int b = blockIdx.x, t = threadIdx.x;
    if (t == 0) carry = 0;
    __syncthreads();
    int rounds = (eb + T - 1) / T;
    for (int jr = 0; jr < rounds; ++jr) {
        int idx = jr * T + t;
        int v = (idx < eb) ? cntT[b * ebp + idx] : 0;
        tsum[t] = v;
        __syncthreads();
        for (int d = 1; d < T; d <<= 1) {
            int o = (t >= d) ? tsum[t - d] : 0;
            __syncthreads();
            tsum[t] += o;
            __syncthreads();
        }
        int excl = tsum[t] - v + carry;
        if (idx < eb) ofsT[b * ebp + idx] = excl;
        __syncthreads();
        if (t == 0) carry += tsum[T - 1];
        __syncthreads();
    }
    if (t == 0) tot[b] = carry;
}

// ---------- scatter: LDS bucket-sort one 2048-edge tile, coalesced copy-out ----------
// record.x = (col & 4095) << 17 | row  (row < 2^17), record.y = bits(w)
__global__ void k_scatter(const int* __restrict__ row, const int* __restrict__ col,
                          const float* __restrict__ w,
                          const int* __restrict__ cntT, const int* __restrict__ ofsT,
                          const int* __restrict__ tot,
                          int2* __restrict__ rec, int E, int nb, int ebp) {
    __shared__ int  lofs[MAXNB + 1];
    __shared__ int  rnk[MAXNB];
    __shared__ int  rbase[MAXNB];
    __shared__ int2 buf[EPB];          // 16 KB
    __shared__ unsigned char bkt[EPB]; // 2 KB
    int t = threadIdx.x, g = blockIdx.x;
    if (t < MAXNB) rnk[t] = 0;
    if (t < 64) {
        // scan padded tot -> bucket bases (exclusive), in-lane
        int tv = (t < nb) ? ((tot[t] + 3) & ~3) : 0;
        int incA = tv;
#pragma unroll
        for (int d = 1; d < 32; d <<= 1) {
            int o = __shfl_up(incA, d, 64);
            if (t >= d) incA += o;
        }
        // scan this block's count row -> tile-local offsets
        int h = (t < nb) ? cntT[t * ebp + g] : 0;
        int incB = h;
#pragma unroll
        for (int d = 1; d < 32; d <<= 1) {
            int o = __shfl_up(incB, d, 64);
            if (t >= d) incB += o;
        }
        if (t == 0) lofs[0] = 0;
        if (t < nb) {
            lofs[t + 1] = incB;
            rbase[t] = (incA - tv) + ofsT[t * ebp + g];   // bstart[b] + my offset
        }
    }
    __syncthreads();

    int base = g * EPB;
    bool full = (base + EPB <= E);
    if (full) {
#pragma unroll
        for (int k = 0; k < EPT / 4; ++k) {
            int idx = base + (t + k * T) * 4;
            int4   c  = *(const int4*)(col + idx);
            int4   r  = *(const int4*)(row + idx);
            float4 wv = *(const float4*)(w + idx);
            int b, rk, pos;
            b = c.x >> BSHIFT; rk = atomicAdd(&rnk[b], 1); pos = lofs[b] + rk;
            buf[pos] = make_int2(((c.x & (BSIZE-1)) << 17) | r.x, __float_as_int(wv.x));
            bkt[pos] = (unsigned char)b;
            b = c.y >> BSHIFT; rk = atomicAdd(&rnk[b], 1); pos = lofs[b] + rk;
            buf[pos] = make_int2(((c.y & (BSIZE-1)) << 17) | r.y, __float_as_int(wv.y));
            bkt[pos] = (unsigned char)b;
            b = c.z >> BSHIFT; rk = atomicAdd(&rnk[b], 1); pos = lofs[b] + rk;
            buf[pos] = make_int2(((c.z & (BSIZE-1)) << 17) | r.z, __float_as_int(wv.z));
            bkt[pos] = (unsigned char)b;
            b = c.w >> BSHIFT; rk = atomicAdd(&rnk[b], 1); pos = lofs[b] + rk;
            buf[pos] = make_int2(((c.w & (BSIZE-1)) << 17) | r.w, __float_as_int(wv.w));
            bkt[pos] = (unsigned char)b;
        }
    } else {
        for (int k = 0; k < EPT; ++k) {
            int e = base + t + k * T;
            if (e < E) {
                int c = col[e];
                int b = c >> BSHIFT;
                int rk = atomicAdd(&rnk[b], 1);
                int pos = lofs[b] + rk;
                buf[pos] = make_int2(((c & (BSIZE-1)) << 17) | row[e], __float_as_int(w[e]));
                bkt[pos] = (unsigned char)b;
            }
        }
    }
    __syncthreads();
    int total = lofs[nb];
    for (int j = t; j < total; j += T) {       // coalesced copy-out
        int b = bkt[j];
        rec[rbase[b] + (j - lofs[b])] = buf[j];
    }
}

// ---------- accumulate: LDS scatter-add of one bucket slice ----------
template <bool HAS_SRC>
__global__ void k_acc(const int2* __restrict__ rec, const int* __restrict__ tot,
                      const float* __restrict__ src, float* __restrict__ part, int nb) {
    __shared__ float acc[BSIZE];
    __shared__ int   bst[MAXNB];
    int t = threadIdx.x, g = blockIdx.x;
    int b = g / M, m = g % M;
    if (t < 64) {                               // bucket bases from padded tot
        int tv = (t < nb) ? ((tot[t] + 3) & ~3) : 0;
        int inc = tv;
#pragma unroll
        for (int d = 1; d < 32; d <<= 1) {
            int o = __shfl_up(inc, d, 64);
            if (t >= d) inc += o;
        }
        if (t < nb) bst[t] = inc - tv;
    }
    for (int j = t; j < BSIZE; j += T) acc[j] = 0.0f;
    __syncthreads();
    int s  = bst[b];
    int tb = tot[b];
    int chunk = ((tb + M - 1) / M + 7) & ~7;    // x8 records per slice
    int lo = s + m * chunk;
    int hi = min(s + tb, lo + chunk);
    const int4* rec4 = (const int4*)rec;
    int i = lo + t * 8;
    for (; i + 7 < hi; i += T * 8) {
        int4 q0 = rec4[(i >> 1) + 0];
        int4 q1 = rec4[(i >> 1) + 1];
        int4 q2 = rec4[(i >> 1) + 2];
        int4 q3 = rec4[(i >> 1) + 3];
        float v0 = __int_as_float(q0.y), v1 = __int_as_float(q0.w);
        float v2 = __int_as_float(q1.y), v3 = __int_as_float(q1.w);
        float v4 = __int_as_float(q2.y), v5 = __int_as_float(q2.w);
        float v6 = __int_as_float(q3.y), v7 = __int_as_float(q3.w);
        if (HAS_SRC) {
            v0 *= src[q0.x & 0x1FFFF]; v1 *= src[q0.z & 0x1FFFF];
            v2 *= src[q1.x & 0x1FFFF]; v3 *= src[q1.z & 0x1FFFF];
            v4 *= src[q2.x & 0x1FFFF]; v5 *= src[q2.z & 0x1FFFF];
            v6 *= src[q3.x & 0x1FFFF]; v7 *= src[q3.z & 0x1FFFF];
        }
        atomicAdd(&acc[((unsigned)q0.x) >> 17], v0);
        atomicAdd(&acc[((unsigned)q0.z) >> 17], v1);
        atomicAdd(&acc[((unsigned)q1.x) >> 17], v2);
        atomicAdd(&acc[((unsigned)q1.z) >> 17], v3);
        atomicAdd(&acc[((unsigned)q2.x) >> 17], v4);
        atomicAdd(&acc[((unsigned)q2.z) >> 17], v5);
        atomicAdd(&acc[((unsigned)q3.x) >> 17], v6);
        atomicAdd(&acc[((unsigned)q3.z) >> 17], v7);
    }
    for (; i < hi; ++i) {                       // tail owned by exactly one thread
        int2 r = rec[i];
        float v = __int_as_float(r.y);
        if (HAS_SRC) v *= src[r.x & 0x1FFFF];
        atomicAdd(&acc[((unsigned)r.x) >> 17], v);
    }
    __syncthreads();
    float* dst = part + (size_t)g * BSIZE;
    for (int j = t; j < BSIZE; j += T) dst[j] = acc[j];
}

// ---------- reduce + pointwise ----------
__device__ __forceinline__ float reduceM(const float* __restrict__ part, int n) {
    int b = n >> BSHIFT, o = n & (BSIZE - 1);
    const float* pp = part + (size_t)b * M * BSIZE + o;
    float s = 0.0f;
#pragma unroll
    for (int m = 0; m < M; ++m) s += pp[(size_t)m * BSIZE];
    return s;
}

__global__ void k_red_dinv(const float* __restrict__ part, const float* __restrict__ x,
                           float* __restrict__ dinv, float* __restrict__ p, int N) {
    int i = blockIdx.x * blockDim.x + threadIdx.x;
    if (i < N) {
        float d  = reduceM(part, i) + 1.0f;     // +1 = self-loop
        float di = rsqrtf(d);
        dinv[i] = di;
        p[i] = di * x[i];
    }
}

__global__ void k_red_mlp(const float* __restrict__ part, const float* __restrict__ dinv,
                          const float* __restrict__ p,
                          const float* __restrict__ W1, const float* __restrict__ b1,
                          const float* __restrict__ W2,
                          float* __restrict__ q, int N) {
    int i = blockIdx.x * blockDim.x + threadIdx.x;
    if (i < N) {
        float di = dinv[i];
        float s  = di * reduceM(part, i) + di * p[i];
        float acc = 0.0f;
#pragma unroll
        for (int k = 0; k < 16; ++k) {
            float h = fmaxf(s * W1[k] + b1[k], 0.0f);
            acc += h * W2[k];
        }
        q[i] = di * acc;
    }
}

__global__ void k_red_out(const float* __restrict__ part, const float* __restrict__ dinv,
                          const float* __restrict__ q, const float* __restrict__ b2,
                          float* __restrict__ out, int N) {
    int i = blockIdx.x * blockDim.x + threadIdx.x;
    if (i < N) {
        float di = dinv[i];
        out[i] = di * reduceM(part, i) + di * q[i] + b2[0];
    }
}

extern "C" void kernel_launch(void* const* d_in, const int* in_sizes, int n_in,
                              void* d_out, int out_size, void* d_ws, size_t ws_size,
                              hipStream_t stream) {
    const float* x  = (const float*)d_in[0];
    const int*   ei = (const int*)  d_in[1];
    const float* ew = (const float*)d_in[2];
    const float* W1 = (const float*)d_in[3];
    const float* b1 = (const float*)d_in[4];
    const float* W2 = (const float*)d_in[5];
    const float* b2 = (const float*)d_in[6];

    const int N = in_sizes[0];       // x is [N,1]
    const int E = in_sizes[2];       // edge_attr is [E]
    const int* row = ei;             // edge_index[0] = source
    const int* col = ei + E;         // edge_index[1] = target
    const int nb  = (N + BSIZE - 1) >> BSHIFT;   // 25
    const int eb  = (E + EPB - 1) / EPB;         // 2442
    const int ebp = (eb + 63) & ~63;             // padded row length

    // workspace layout (~55.1 MB), 256 B aligned
    char* wsp = (char*)d_ws;
    auto take = [&](size_t bytes) {
        char* r = wsp; wsp += (bytes + 255) & ~(size_t)255; return (void*)r;
    };
    int2*  rec  = (int2*) take((size_t)(E + 4 * MAXNB) * 8);   // 40.07 MB
    float* part = (float*)take((size_t)nb * M * BSIZE * 4);    // 13.11 MB
    float* dinv = (float*)take((size_t)N * 4);
    float* p    = (float*)take((size_t)N * 4);
    float* q    = (float*)take((size_t)N * 4);
    int*   cntT = (int*)  take((size_t)MAXNB * ebp * 4);       // 0.32 MB
    int*   ofsT = (int*)  take((size_t)MAXNB * ebp * 4);       // 0.32 MB
    int*   tot  = (int*)  take(MAXNB * 4);

    float* out = (float*)d_out;

    const int nbk = (N + T - 1) / T;
    const int ab  = nb * M;                      // 800

    k_count  <<<eb, T, 0, stream>>>(col, cntT, E, nb, ebp);
    k_scan   <<<nb, T, 0, stream>>>(cntT, ofsT, tot, eb, ebp);
    k_scatter<<<eb, T, 0, stream>>>(row, col, ew, cntT, ofsT, tot, rec, E, nb, ebp);

    // degree
    k_acc<false><<<ab, T, 0, stream>>>(rec, tot, nullptr, part, nb);
    k_red_dinv  <<<nbk, T, 0, stream>>>(part, x, dinv, p, N);

    // layer 1
    k_acc<true><<<ab, T, 0, stream>>>(rec, tot, p, part, nb);
    k_red_mlp  <<<nbk, T, 0, stream>>>(part, dinv, p, W1, b1, W2, q, N);

    // layer 2
    k_acc<true><<<ab, T, 0, stream>>>(rec, tot, q, part, nb);
    k_red_out  <<<nbk, T, 0, stream>>>(part, dinv, q, b2, out, N);
}